// Round 10
// baseline (61.501 us; speedup 1.0000x reference)
//
#include <hip/hip_runtime.h>
#include <hip/hip_bf16.h>
#include <math.h>

#define BB 2
#define NN 2048
#define FF 128
#define HH 4
#define HALF 1024

typedef __attribute__((ext_vector_type(8))) short short8;
typedef __attribute__((ext_vector_type(16))) short short16;
typedef __attribute__((ext_vector_type(4))) float f32x4;

__device__ __forceinline__ short f2bf(float f){
    __hip_bfloat16 h = __float2bfloat16(f);
    return *reinterpret_cast<short*>(&h);
}
__device__ __forceinline__ float bf2f(short v){
    __hip_bfloat16 h = *reinterpret_cast<__hip_bfloat16*>(&v);
    return __bfloat162float(h);
}

// K0: wv fp32 -> wvB (bf16 row-major) + wvT (bf16 transpose)
__global__ void k_wvt(const float* __restrict__ wv, __hip_bfloat16* __restrict__ wvT,
                      __hip_bfloat16* __restrict__ wvB){
    __shared__ float tile[32][33];
    int b = blockIdx.z;
    int i0 = blockIdx.x * 32, j0 = blockIdx.y * 32;
    int tx = threadIdx.x & 31, ty = threadIdx.x >> 5;
    const float* src = wv + (size_t)b * HALF * HALF;
    __hip_bfloat16* dstT = wvT + (size_t)b * HALF * HALF;
    __hip_bfloat16* dstB = wvB + (size_t)b * HALF * HALF;
    #pragma unroll
    for(int l = 0; l < 4; l++){
        int row = ty + l * 8;
        float v = src[(size_t)(j0 + row) * HALF + (i0 + tx)];
        tile[row][tx] = v;
        dstB[(size_t)(j0 + row) * HALF + (i0 + tx)] = __float2bfloat16(v);
    }
    __syncthreads();
    #pragma unroll
    for(int l = 0; l < 4; l++){
        int row = ty + l * 8;
        dstT[(size_t)(i0 + row) * HALF + (j0 + tx)] = __float2bfloat16(tile[tx][row]);
    }
}

// K1: x @ W[h] via MFMA -> WhB (bf16 B-fragment layout, UNSCALED) + sT/dT + denom zero.
// grid (32, 4, 2), block 256 = 4 waves (wm=w>>1, wn=w&1). No fp32 Wh output.
__global__ __launch_bounds__(256) void k_whmm(const float* __restrict__ x,
        const float* __restrict__ W, const float* __restrict__ a,
        short* __restrict__ WhB, float* __restrict__ sT, float* __restrict__ dT,
        float* __restrict__ denom){
    __shared__ short xs[64 * 136];
    __shared__ short ws_[128 * 130];
    __shared__ float red_s[2][64], red_d[2][64];
    int t = threadIdx.x;
    int w = t >> 6, lane = t & 63;
    int wm = w >> 1, wn = w & 1;
    int n0 = blockIdx.x * 64;
    int h = blockIdx.y, b = blockIdx.z;
    int sl = b * HH + h;
    // zero denom (16384 entries / 256 blocks = 64 each)
    int flat = blockIdx.x + 32 * (blockIdx.y + HH * blockIdx.z);
    if(t < 64) denom[flat * 64 + t] = 0.f;
    // stage x tile (64x128 fp32 -> bf16)
    const float* xb = x + ((size_t)b * NN + n0) * FF;
    #pragma unroll
    for(int l = 0; l < 8; l++){
        int flat4 = t + l * 256;
        int row = flat4 >> 5, col4 = flat4 & 31;
        float4 v = *(const float4*)(xb + (size_t)row * FF + col4 * 4);
        short* dst = &xs[row * 136 + col4 * 4];
        dst[0] = f2bf(v.x); dst[1] = f2bf(v.y); dst[2] = f2bf(v.z); dst[3] = f2bf(v.w);
    }
    // stage W[h]
    const float* Wb = W + (size_t)h * FF * FF;
    #pragma unroll
    for(int l = 0; l < 16; l++){
        int flat4 = t + l * 256;
        int row = flat4 >> 5, col4 = flat4 & 31;
        float4 v = *(const float4*)(Wb + (size_t)row * FF + col4 * 4);
        short* dst = &ws_[row * 130 + col4 * 4];
        dst[0] = f2bf(v.x); dst[1] = f2bf(v.y); dst[2] = f2bf(v.z); dst[3] = f2bf(v.w);
    }
    __syncthreads();
    int m = lane & 15, q = lane >> 4;
    f32x4 acc[2][4] = {};
    #pragma unroll
    for(int ks = 0; ks < 4; ks++){
        short8 af[2];
        #pragma unroll
        for(int mi = 0; mi < 2; mi++)
            af[mi] = *(const short8*)&xs[(wm * 32 + mi * 16 + m) * 136 + ks * 32 + q * 8];
        short8 bf[4];
        #pragma unroll
        for(int ni = 0; ni < 4; ni++){
            #pragma unroll
            for(int e = 0; e < 8; e++)
                bf[ni][e] = ws_[(ks * 32 + q * 8 + e) * 130 + wn * 64 + ni * 16 + m];
        }
        #pragma unroll
        for(int mi = 0; mi < 2; mi++)
            #pragma unroll
            for(int ni = 0; ni < 4; ni++)
                acc[mi][ni] = __builtin_amdgcn_mfma_f32_16x16x32_bf16(af[mi], bf[ni], acc[mi][ni], 0, 0, 0);
    }
    // s/d dots from accumulators
    float asrc[4], adst[4];
    const float* ah = a + (size_t)h * 2 * FF;
    #pragma unroll
    for(int ni = 0; ni < 4; ni++){
        int col = wn * 64 + ni * 16 + m;
        asrc[ni] = ah[col];
        adst[ni] = ah[FF + col];
    }
    #pragma unroll
    for(int mi = 0; mi < 2; mi++){
        #pragma unroll
        for(int rg = 0; rg < 4; rg++){
            float ps = 0.f, pd = 0.f;
            #pragma unroll
            for(int ni = 0; ni < 4; ni++){
                ps += acc[mi][ni][rg] * asrc[ni];
                pd += acc[mi][ni][rg] * adst[ni];
            }
            #pragma unroll
            for(int msk = 8; msk >= 1; msk >>= 1){
                ps += __shfl_xor(ps, msk);
                pd += __shfl_xor(pd, msk);
            }
            if(m == 0){
                int row = wm * 32 + mi * 16 + q * 4 + rg;
                red_s[wn][row] = ps;
                red_d[wn][row] = pd;
            }
        }
    }
    __syncthreads();   // red_s/red_d ready; all xs/ws_ reads complete
    // bounce acc -> cs (reuse xs region) as bf16 [64][130]
    short* cs = xs;
    #pragma unroll
    for(int mi = 0; mi < 2; mi++){
        #pragma unroll
        for(int ni = 0; ni < 4; ni++){
            int col = wn * 64 + ni * 16 + m;
            #pragma unroll
            for(int rg = 0; rg < 4; rg++){
                int row = wm * 32 + mi * 16 + q * 4 + rg;
                cs[row * 130 + col] = f2bf(acc[mi][ni][rg]);
            }
        }
    }
    if(t < 64){
        int n = n0 + t;
        sT[((size_t)b * NN + n) * HH + h] = red_s[0][t] + red_s[1][t];
        dT[((size_t)b * NN + n) * HH + h] = red_d[0][t] + red_d[1][t];
    }
    __syncthreads();
    // read out B-fragments: 16 frags (ktg 0..1, nt 0..7), wave w -> frags w*4..w*4+3
    #pragma unroll
    for(int fi = 0; fi < 4; fi++){
        int fragId = w * 4 + fi;
        int ktg = fragId >> 3, nt = fragId & 7;
        short8 pk;
        #pragma unroll
        for(int e = 0; e < 8; e++)
            pk[e] = cs[(ktg * 32 + q * 8 + e) * 130 + nt * 16 + m];
        *(short8*)(WhB + (((size_t)sl * 8 + nt) * 64 + blockIdx.x * 2 + ktg) * 512 + lane * 8) = pk;
    }
}

// K2: column denominators only (no P store). grid (8, 32, 4), block 256.
__global__ __launch_bounds__(256) void k_denom(const int* __restrict__ adj,
        const __hip_bfloat16* __restrict__ wvB, const __hip_bfloat16* __restrict__ wvT,
        const float* __restrict__ sT, const float* __restrict__ dT,
        float* __restrict__ denom){
    __shared__ float red[HH][128];
    int t = threadIdx.x;
    int jlane = t & 127, ihalf = t >> 7;
    int jt = blockIdx.x, ic = blockIdx.y, bb = blockIdx.z;
    int b = bb >> 1, blk = bb & 1;
    int jl = jt * 128 + jlane;
    int jg = blk ? jl : HALF + jl;
    int iloc0 = ic * 32 + ihalf * 16;
    int ig0 = (blk ? HALF : 0) + iloc0;
    const int* ap = adj + ((size_t)b * NN + ig0) * NN + jg;
    const short* wp = (const short*)(blk ? wvB : wvT) + ((size_t)b * HALF + iloc0) * HALF + jl;
    const float* sp = sT + ((size_t)b * NN + ig0) * HH;
    float4 dv4 = *(const float4*)(dT + ((size_t)b * NN + jg) * HH);
    float da[4] = {dv4.x, dv4.y, dv4.z, dv4.w};
    float den[HH] = {};
    #pragma unroll 4
    for(int ii = 0; ii < 16; ii++){
        int av = ap[(size_t)ii * NN];
        short wq = wp[(size_t)ii * HALF];
        float4 s4 = *(const float4*)(sp + ii * HH);
        float wmv = av > 0 ? bf2f(wq) : 0.f;
        float sa[4] = {s4.x, s4.y, s4.z, s4.w};
        #pragma unroll
        for(int h = 0; h < HH; h++){
            float tt = sa[h] + da[h];
            tt = tt > 0.f ? tt : 0.2f * tt;
            den[h] += __expf(tt) * wmv;
        }
    }
    if(ihalf){
        #pragma unroll
        for(int h = 0; h < HH; h++) red[h][jlane] = den[h];
    }
    __syncthreads();
    if(!ihalf){
        #pragma unroll
        for(int h = 0; h < HH; h++)
            atomicAdd(&denom[((size_t)b * HH + h) * NN + jg], den[h] + red[h][jlane]);
    }
}

// K3: FUSED att+PV: P tile recomputed into LDS (row-major streaming), MFMA vs WhB.
// grid (16 mt, 4 h, 4 bb), block 512 = 8 waves (wm = w>>1 in 0..3, wn = w&1).
// Per j-tile: {convert exp -> Ps, stage Bs, prefetch t+1} barrier {16 MFMAs} barrier.
__global__ __launch_bounds__(512) void k_attpv(const int* __restrict__ adj,
        const __hip_bfloat16* __restrict__ wvB, const __hip_bfloat16* __restrict__ wvT,
        const float* __restrict__ sT, const float* __restrict__ dT,
        const float* __restrict__ denom, const short* __restrict__ WhB,
        float* __restrict__ out){
    __shared__ short Ps[64 * 72];     // [i 64][j 64 +8 pad] bf16
    __shared__ short Bs[16 * 512];    // 16 frags (kt 2 x nt 8)
    int t = threadIdx.x;
    int w = t >> 6, lane = t & 63;
    int wm = w >> 1, wn = w & 1;
    int mt = blockIdx.x, h = blockIdx.y, bb = blockIdx.z;
    int b = bb >> 1, blk = bb & 1;
    int sl = b * HH + h;
    int iloc0 = mt * 64;
    int igb = (blk ? HALF : 0) + iloc0;
    int col0 = blk ? 0 : HALF;
    int koff = blk ? 0 : 32;
    // phase-A geometry: thread owns row iA, 8 consecutive j
    int iA = t >> 3, jj = t & 7, j8 = jj * 8;
    const int* apb = adj + ((size_t)b * NN + igb + iA) * NN + col0;
    const short* wpb = (const short*)(blk ? wvB : wvT) + ((size_t)b * HALF + iloc0 + iA) * HALF;
    const float* dpb = dT + ((size_t)b * NN + col0) * HH + h;
    const float* npb = denom + (size_t)sl * NN + col0;
    float sA = sT[((size_t)b * NN + igb + iA) * HH + h];
    // Bs staging geometry: thread stages 32B of one frag
    int fragI = t >> 5;               // 0..15 = kt*8 + nt
    int ktf = fragI >> 3, ntf = fragI & 7;
    int ln2 = (t & 31) * 2;
    const short* Bsrc = WhB + (((size_t)sl * 8 + ntf) * 64 + koff + ktf) * 512 + ln2 * 8;
    // pipeline regs
    int4 A0, A1; short8 WQ; short16 BV;
    float dA[8], nA[8];
#define LOADT(JT) { \
    A0 = *(const int4*)(apb + (size_t)(JT) * 64 + j8); \
    A1 = *(const int4*)(apb + (size_t)(JT) * 64 + j8 + 4); \
    WQ = *(const short8*)(wpb + (JT) * 64 + j8); \
    _Pragma("unroll") \
    for(int e_ = 0; e_ < 8; e_++) dA[e_] = dpb[((JT) * 64 + j8 + e_) * HH]; \
    float4 n0_ = *(const float4*)(npb + (JT) * 64 + j8); \
    float4 n1_ = *(const float4*)(npb + (JT) * 64 + j8 + 4); \
    nA[0]=n0_.x; nA[1]=n0_.y; nA[2]=n0_.z; nA[3]=n0_.w; \
    nA[4]=n1_.x; nA[5]=n1_.y; nA[6]=n1_.z; nA[7]=n1_.w; \
    BV = *(const short16*)(Bsrc + (size_t)(JT) * 1024); }
    f32x4 acc[4] = {};
    LOADT(0)
    for(int jt = 0; jt < 16; jt++){
        int aa[8] = {A0.x, A0.y, A0.z, A0.w, A1.x, A1.y, A1.z, A1.w};
        short8 pk;
        #pragma unroll
        for(int e = 0; e < 8; e++){
            float wmv = aa[e] > 0 ? bf2f(WQ[e]) : 0.f;
            float inv = 1.f / fmaxf(nA[e], 1e-12f);
            float tt = sA + dA[e];
            tt = tt > 0.f ? tt : 0.2f * tt;
            pk[e] = f2bf(__expf(tt) * wmv * inv);
        }
        __syncthreads();              // consumers of previous tile done
        *(short8*)&Ps[iA * 72 + j8] = pk;
        *(short16*)&Bs[fragI * 512 + ln2 * 8] = BV;
        if(jt < 15){ LOADT(jt + 1) }  // in flight across MFMA phase
        __syncthreads();              // Ps/Bs ready
        int m = lane & 15, q = lane >> 4;
        short8 af0 = *(const short8*)&Ps[(wm * 16 + m) * 72 + q * 8];
        short8 af1 = *(const short8*)&Ps[(wm * 16 + m) * 72 + 32 + q * 8];
        #pragma unroll
        for(int ni = 0; ni < 4; ni++){
            short8 bf0 = *(const short8*)&Bs[((wn * 4 + ni) * 64 + lane) * 8];
            short8 bf1 = *(const short8*)&Bs[((8 + wn * 4 + ni) * 64 + lane) * 8];
            acc[ni] = __builtin_amdgcn_mfma_f32_16x16x32_bf16(af0, bf0, acc[ni], 0, 0, 0);
            acc[ni] = __builtin_amdgcn_mfma_f32_16x16x32_bf16(af1, bf1, acc[ni], 0, 0, 0);
        }
    }
#undef LOADT
    // epilogue: C/D col = lane&15 (f), row = (lane>>4)*4 + rg
    int q = lane >> 4, rc = lane & 15;
    #pragma unroll
    for(int ni = 0; ni < 4; ni++){
        int f = wn * 64 + ni * 16 + rc;
        #pragma unroll
        for(int rg = 0; rg < 4; rg++){
            int grow = igb + wm * 16 + q * 4 + rg;
            float v = acc[ni][rg];
            v = v > 0.f ? v : expm1f(v);
            out[((size_t)b * NN + grow) * (HH * FF) + h * FF + f] = v;
        }
    }
}

extern "C" void kernel_launch(void* const* d_in, const int* in_sizes, int n_in,
                              void* d_out, int out_size, void* d_ws, size_t ws_size,
                              hipStream_t stream){
    const float* x   = (const float*)d_in[0];
    const float* wv  = (const float*)d_in[1];
    const float* W   = (const float*)d_in[2];
    const float* a   = (const float*)d_in[3];
    const int*   adj = (const int*)d_in[4];
    float* out = (float*)d_out;

    char* ws = (char*)d_ws;
    short*          WhB   = (short*)ws;                          // 4,194,304 B
    __hip_bfloat16* wvT   = (__hip_bfloat16*)(ws + 4194304);     // 4,194,304 B
    __hip_bfloat16* wvB   = (__hip_bfloat16*)(ws + 8388608);     // 4,194,304 B
    float*          sT    = (float*)(ws + 12582912);             //    65,536 B
    float*          dT    = (float*)(ws + 12648448);             //    65,536 B
    float*          denom = (float*)(ws + 12713984);             //    65,536 B

    k_wvt<<<dim3(32, 32, BB), 256, 0, stream>>>(wv, wvT, wvB);
    k_whmm<<<dim3(32, HH, BB), 256, 0, stream>>>(x, W, a, WhB, sT, dT, denom);
    k_denom<<<dim3(8, 32, 4), 256, 0, stream>>>(adj, wvB, wvT, sT, dT, denom);
    k_attpv<<<dim3(16, HH, 4), 512, 0, stream>>>(adj, wvB, wvT, sT, dT, denom, WhB, out);
}

// Round 11
// 47.896 us; speedup vs baseline: 1.2841x; 1.2841x over previous
//
#include <hip/hip_runtime.h>
#include <hip/hip_bf16.h>
#include <math.h>

#define BB 2
#define NN 2048
#define FF 128
#define HH 4
#define HALF 1024

typedef __attribute__((ext_vector_type(8))) short short8;
typedef __attribute__((ext_vector_type(4))) short short4v;
typedef __attribute__((ext_vector_type(4))) float f32x4;

__device__ __forceinline__ short f2bf(float f){
    __hip_bfloat16 h = __float2bfloat16(f);
    return *reinterpret_cast<short*>(&h);
}
__device__ __forceinline__ float bf2f(short v){
    __hip_bfloat16 h = *reinterpret_cast<__hip_bfloat16*>(&v);
    return __bfloat162float(h);
}

// K1: x @ W[h] via MFMA -> WhB (bf16 B-fragment layout, UNSCALED) + sT/dT + denom zero.
// grid (32, 4, 2), block 256 = 4 waves (wm=w>>1, wn=w&1). No fp32 Wh output.
__global__ __launch_bounds__(256) void k_whmm(const float* __restrict__ x,
        const float* __restrict__ W, const float* __restrict__ a,
        short* __restrict__ WhB, float* __restrict__ sT, float* __restrict__ dT,
        float* __restrict__ denom){
    __shared__ short xs[64 * 136];
    __shared__ short ws_[128 * 130];
    __shared__ float red_s[2][64], red_d[2][64];
    int t = threadIdx.x;
    int w = t >> 6, lane = t & 63;
    int wm = w >> 1, wn = w & 1;
    int n0 = blockIdx.x * 64;
    int h = blockIdx.y, b = blockIdx.z;
    int sl = b * HH + h;
    // zero denom (16384 entries / 256 blocks = 64 each)
    int flat = blockIdx.x + 32 * (blockIdx.y + HH * blockIdx.z);
    if(t < 64) denom[flat * 64 + t] = 0.f;
    // stage x tile (64x128 fp32 -> bf16)
    const float* xb = x + ((size_t)b * NN + n0) * FF;
    #pragma unroll
    for(int l = 0; l < 8; l++){
        int flat4 = t + l * 256;
        int row = flat4 >> 5, col4 = flat4 & 31;
        float4 v = *(const float4*)(xb + (size_t)row * FF + col4 * 4);
        short* dst = &xs[row * 136 + col4 * 4];
        dst[0] = f2bf(v.x); dst[1] = f2bf(v.y); dst[2] = f2bf(v.z); dst[3] = f2bf(v.w);
    }
    // stage W[h]
    const float* Wb = W + (size_t)h * FF * FF;
    #pragma unroll
    for(int l = 0; l < 16; l++){
        int flat4 = t + l * 256;
        int row = flat4 >> 5, col4 = flat4 & 31;
        float4 v = *(const float4*)(Wb + (size_t)row * FF + col4 * 4);
        short* dst = &ws_[row * 130 + col4 * 4];
        dst[0] = f2bf(v.x); dst[1] = f2bf(v.y); dst[2] = f2bf(v.z); dst[3] = f2bf(v.w);
    }
    __syncthreads();
    int m = lane & 15, q = lane >> 4;
    f32x4 acc[2][4] = {};
    #pragma unroll
    for(int ks = 0; ks < 4; ks++){
        short8 af[2];
        #pragma unroll
        for(int mi = 0; mi < 2; mi++)
            af[mi] = *(const short8*)&xs[(wm * 32 + mi * 16 + m) * 136 + ks * 32 + q * 8];
        short8 bf[4];
        #pragma unroll
        for(int ni = 0; ni < 4; ni++){
            #pragma unroll
            for(int e = 0; e < 8; e++)
                bf[ni][e] = ws_[(ks * 32 + q * 8 + e) * 130 + wn * 64 + ni * 16 + m];
        }
        #pragma unroll
        for(int mi = 0; mi < 2; mi++)
            #pragma unroll
            for(int ni = 0; ni < 4; ni++)
                acc[mi][ni] = __builtin_amdgcn_mfma_f32_16x16x32_bf16(af[mi], bf[ni], acc[mi][ni], 0, 0, 0);
    }
    // s/d dots from accumulators
    float asrc[4], adst[4];
    const float* ah = a + (size_t)h * 2 * FF;
    #pragma unroll
    for(int ni = 0; ni < 4; ni++){
        int col = wn * 64 + ni * 16 + m;
        asrc[ni] = ah[col];
        adst[ni] = ah[FF + col];
    }
    #pragma unroll
    for(int mi = 0; mi < 2; mi++){
        #pragma unroll
        for(int rg = 0; rg < 4; rg++){
            float ps = 0.f, pd = 0.f;
            #pragma unroll
            for(int ni = 0; ni < 4; ni++){
                ps += acc[mi][ni][rg] * asrc[ni];
                pd += acc[mi][ni][rg] * adst[ni];
            }
            #pragma unroll
            for(int msk = 8; msk >= 1; msk >>= 1){
                ps += __shfl_xor(ps, msk);
                pd += __shfl_xor(pd, msk);
            }
            if(m == 0){
                int row = wm * 32 + mi * 16 + q * 4 + rg;
                red_s[wn][row] = ps;
                red_d[wn][row] = pd;
            }
        }
    }
    __syncthreads();   // red_s/red_d ready; all xs/ws_ reads complete
    // bounce acc -> cs (reuse xs region) as bf16 [64][130]
    short* cs = xs;
    #pragma unroll
    for(int mi = 0; mi < 2; mi++){
        #pragma unroll
        for(int ni = 0; ni < 4; ni++){
            int col = wn * 64 + ni * 16 + m;
            #pragma unroll
            for(int rg = 0; rg < 4; rg++){
                int row = wm * 32 + mi * 16 + q * 4 + rg;
                cs[row * 130 + col] = f2bf(acc[mi][ni][rg]);
            }
        }
    }
    if(t < 64){
        int n = n0 + t;
        sT[((size_t)b * NN + n) * HH + h] = red_s[0][t] + red_s[1][t];
        dT[((size_t)b * NN + n) * HH + h] = red_d[0][t] + red_d[1][t];
    }
    __syncthreads();
    // read out B-fragments: 16 frags (ktg 0..1, nt 0..7), wave w -> frags w*4..w*4+3
    #pragma unroll
    for(int fi = 0; fi < 4; fi++){
        int fragId = w * 4 + fi;
        int ktg = fragId >> 3, nt = fragId & 7;
        short8 pk;
        #pragma unroll
        for(int e = 0; e < 8; e++)
            pk[e] = cs[(ktg * 32 + q * 8 + e) * 130 + nt * 16 + m];
        *(short8*)(WhB + (((size_t)sl * 8 + nt) * 64 + blockIdx.x * 2 + ktg) * 512 + lane * 8) = pk;
    }
}

// K2: ROW-MAJOR streaming attention from RAW fp32 wv: P[slice][i][j] bf16 (UNSCALED)
// + column denom atomics. grid (8, 32, 4), block 256 (jlane 128 x ihalf 2).
__global__ __launch_bounds__(256) void k_att(const int* __restrict__ adj,
        const float* __restrict__ wv,
        const float* __restrict__ sT, const float* __restrict__ dT,
        short* __restrict__ P, float* __restrict__ denom){
    __shared__ float red[HH][128];
    int t = threadIdx.x;
    int jlane = t & 127, ihalf = t >> 7;
    int jt = blockIdx.x, ic = blockIdx.y, bb = blockIdx.z;
    int b = bb >> 1, blk = bb & 1;
    int jl = jt * 128 + jlane;
    int jg = blk ? jl : HALF + jl;
    int iloc0 = ic * 32 + ihalf * 16;
    int ig0 = (blk ? HALF : 0) + iloc0;
    const int* ap = adj + ((size_t)b * NN + ig0) * NN + jg;
    const float* sp = sT + ((size_t)b * NN + ig0) * HH;
    float4 dv4 = *(const float4*)(dT + ((size_t)b * NN + jg) * HH);
    float da[4] = {dv4.x, dv4.y, dv4.z, dv4.w};
    short* Pp = P + ((size_t)(bb * HH) << 20) + (size_t)iloc0 * 1024 + jl;
    float den[HH] = {};
#define ATTLOOP(WPTR, WSTRIDE) \
    _Pragma("unroll 4") \
    for(int ii = 0; ii < 16; ii++){ \
        int av = ap[(size_t)ii * NN]; \
        float wq = (WPTR)[(size_t)ii * (WSTRIDE)]; \
        float4 s4 = *(const float4*)(sp + ii * HH); \
        float wmv = av > 0 ? wq : 0.f; \
        float sa[4] = {s4.x, s4.y, s4.z, s4.w}; \
        _Pragma("unroll") \
        for(int h = 0; h < HH; h++){ \
            float tt = sa[h] + da[h]; \
            tt = tt > 0.f ? tt : 0.2f * tt; \
            float pe = __expf(tt) * wmv; \
            den[h] += pe; \
            Pp[((size_t)h << 20) + (size_t)ii * 1024] = f2bf(pe); \
        } \
    }
    if(blk){
        const float* wp = wv + ((size_t)b * HALF + iloc0) * HALF + jl;
        ATTLOOP(wp, HALF)
    } else {
        const float* wp = wv + ((size_t)b * HALF + jl) * HALF + iloc0;
        ATTLOOP(wp, 1)
    }
#undef ATTLOOP
    if(ihalf){
        #pragma unroll
        for(int h = 0; h < HH; h++) red[h][jlane] = den[h];
    }
    __syncthreads();
    if(!ihalf){
        #pragma unroll
        for(int h = 0; h < HH; h++)
            atomicAdd(&denom[((size_t)b * HH + h) * NN + jg], den[h] + red[h][jlane]);
    }
}

// K3: out = ELU((P*inv) @ WhB). BM=32, grid (32,4,4)=512 blocks, 4 waves (2m x 2n).
// A staged from row-major P via 64B row-segments, SCALED by rcp(denom_j) at WRITEST.
__global__ __launch_bounds__(256) void k_pv(const short* __restrict__ P,
        const float* __restrict__ denom, const short* __restrict__ WhB,
        float* __restrict__ out){
    __shared__ short lds[2][6656];
    int t = threadIdx.x;
    int w = t >> 6, lane = t & 63;
    int wm = w >> 1, wn = w & 1;
    int mt = blockIdx.x, h = blockIdx.y, bb = blockIdx.z;
    int b = bb >> 1, blk = bb & 1;
    int sl = b * HH + h;
    const short* Prow = P + ((size_t)(bb * HH + h) << 20);
    size_t Bb2 = ((size_t)sl) * 8;
    int koff = blk ? 0 : 32;           // local k-tile -> global k-tile
    int col0 = blk ? 0 : HALF;         // local col -> global col
    const float* npb = denom + (size_t)sl * NN + col0;
    int rowA = t >> 3, c8 = t & 7;
    const short* srcA0 = Prow + (size_t)(mt * 32 + rowA) * 1024 + c8 * 4;
    f32x4 acc[4] = {};
    short4v r0; short8 r1, r2; float4 n4;
#define LOADST(KT) { \
    r0 = *(const short4v*)(srcA0 + (KT) * 32); \
    n4 = *(const float4*)(npb + (KT) * 32 + c8 * 4); \
    r1 = *(const short8*)(WhB + ((Bb2 + (t >> 6)) * 64 + koff + (KT)) * 512 + (t & 63) * 8); \
    r2 = *(const short8*)(WhB + ((Bb2 + 4 + (t >> 6)) * 64 + koff + (KT)) * 512 + (t & 63) * 8); }
#define WRITEST(BUF) { \
    short4v rs_; \
    rs_[0] = f2bf(bf2f(r0[0]) * __builtin_amdgcn_rcpf(fmaxf(n4.x, 1e-12f))); \
    rs_[1] = f2bf(bf2f(r0[1]) * __builtin_amdgcn_rcpf(fmaxf(n4.y, 1e-12f))); \
    rs_[2] = f2bf(bf2f(r0[2]) * __builtin_amdgcn_rcpf(fmaxf(n4.z, 1e-12f))); \
    rs_[3] = f2bf(bf2f(r0[3]) * __builtin_amdgcn_rcpf(fmaxf(n4.w, 1e-12f))); \
    *(short4v*)&lds[BUF][rowA * 40 + c8 * 4] = rs_; \
    *(short8*)&lds[BUF][2560 + (t >> 6) * 512 + (t & 63) * 8] = r1; \
    *(short8*)&lds[BUF][2560 + 2048 + (t >> 6) * 512 + (t & 63) * 8] = r2; }
    LOADST(0)
    WRITEST(0)
    __syncthreads();
    int m = lane & 15, q = lane >> 4;
    for(int kt = 0; kt < 32; kt++){
        int cur = kt & 1;
        if(kt < 31){ LOADST(kt + 1) }
        short8 af = *(const short8*)&lds[cur][(wm * 16 + m) * 40 + q * 8];
        short8 bf[4];
        #pragma unroll
        for(int ni = 0; ni < 4; ni++)
            bf[ni] = *(const short8*)&lds[cur][2560 + (wn * 4 + ni) * 512 + lane * 8];
        #pragma unroll
        for(int ni = 0; ni < 4; ni++)
            acc[ni] = __builtin_amdgcn_mfma_f32_16x16x32_bf16(af, bf[ni], acc[ni], 0, 0, 0);
        __syncthreads();
        if(kt < 31){
            WRITEST(cur ^ 1)
            __syncthreads();
        }
    }
    int rq = lane >> 4, rc = lane & 15;
    int rowg0 = (blk ? HALF : 0) + mt * 32 + wm * 16;
    #pragma unroll
    for(int ni = 0; ni < 4; ni++){
        int f = (wn * 4 + ni) * 16 + rc;
        #pragma unroll
        for(int rg = 0; rg < 4; rg++){
            float v = acc[ni][rg];
            v = v > 0.f ? v : expm1f(v);
            out[((size_t)b * NN + rowg0 + rq * 4 + rg) * (HH * FF) + h * FF + f] = v;
        }
    }
#undef LOADST
#undef WRITEST
}

extern "C" void kernel_launch(void* const* d_in, const int* in_sizes, int n_in,
                              void* d_out, int out_size, void* d_ws, size_t ws_size,
                              hipStream_t stream){
    const float* x   = (const float*)d_in[0];
    const float* wv  = (const float*)d_in[1];
    const float* W   = (const float*)d_in[2];
    const float* a   = (const float*)d_in[3];
    const int*   adj = (const int*)d_in[4];
    float* out = (float*)d_out;

    char* ws = (char*)d_ws;
    short* P     = (short*)ws;                   // 33,554,432 B
    short* WhB   = (short*)(ws + 33554432);      //  4,194,304 B
    float* sT    = (float*)(ws + 37748736);      //     65,536 B
    float* dT    = (float*)(ws + 37814272);      //     65,536 B
    float* denom = (float*)(ws + 37879808);      //     65,536 B

    k_whmm<<<dim3(32, HH, BB), 256, 0, stream>>>(x, W, a, WhB, sT, dT, denom);
    k_att<<<dim3(8, 32, 4), 256, 0, stream>>>(adj, wv, sT, dT, P, denom);
    k_pv<<<dim3(32, HH, 4), 256, 0, stream>>>(P, denom, WhB, out);
}